// Round 1
// baseline (417.683 us; speedup 1.0000x reference)
//
#include <hip/hip_runtime.h>

#define NTH 256

__global__ __launch_bounds__(NTH) void gauss_cov_kernel(
    const float* __restrict__ rot,
    const float* __restrict__ scale,
    float* __restrict__ out,
    long long n)
{
    __shared__ float smem[NTH * 9];

    const int tid = threadIdx.x;
    const long long base = (long long)blockIdx.x * NTH;
    const long long i = base + tid;

    // ---- stage scale (stride-3 per element) via coalesced LDS staging ----
    const float* sp = scale + base * 3;
    const long long srem = 3LL * n - base * 3;   // floats remaining in scale
    #pragma unroll
    for (int k = 0; k < 3; ++k) {
        int idx = tid + k * NTH;
        smem[idx] = (idx < srem) ? sp[idx] : 0.0f;
    }
    __syncthreads();
    const float s0 = smem[tid * 3 + 0];
    const float s1 = smem[tid * 3 + 1];
    const float s2 = smem[tid * 3 + 2];

    // ---- quaternion load: aligned float4, perfectly coalesced ----
    float c00 = 0.f, c01 = 0.f, c02 = 0.f, c11 = 0.f, c12 = 0.f, c22 = 0.f;
    if (i < n) {
        const float4 q = *reinterpret_cast<const float4*>(rot + i * 4);
        float w = q.x, x = q.y, y = q.z, z = q.w;
        const float inv = rsqrtf(w * w + x * x + y * y + z * z);
        w *= inv; x *= inv; y *= inv; z *= inv;

        const float r00 = 1.f - 2.f * (y * y + z * z);
        const float r01 = 2.f * (x * y - w * z);
        const float r02 = 2.f * (x * z + w * y);
        const float r10 = 2.f * (x * y + w * z);
        const float r11 = 1.f - 2.f * (x * x + z * z);
        const float r12 = 2.f * (y * z - w * x);
        const float r20 = 2.f * (x * z - w * y);
        const float r21 = 2.f * (y * z + w * x);
        const float r22 = 1.f - 2.f * (x * x + y * y);

        const float m00 = r00 * s0, m01 = r01 * s1, m02 = r02 * s2;
        const float m10 = r10 * s0, m11 = r11 * s1, m12 = r12 * s2;
        const float m20 = r20 * s0, m21 = r21 * s1, m22 = r22 * s2;

        c00 = m00 * m00 + m01 * m01 + m02 * m02;
        c01 = m00 * m10 + m01 * m11 + m02 * m12;
        c02 = m00 * m20 + m01 * m21 + m02 * m22;
        c11 = m10 * m10 + m11 * m11 + m12 * m12;
        c12 = m10 * m20 + m11 * m21 + m12 * m22;
        c22 = m20 * m20 + m21 * m21 + m22 * m22;
    }

    // ---- stage symmetric 3x3 into LDS (stride-9: gcd(9,32)=1 -> 2-way, free) ----
    __syncthreads();   // scale region of smem is being overwritten below
    float* row = smem + tid * 9;
    row[0] = c00; row[1] = c01; row[2] = c02;
    row[3] = c01; row[4] = c11; row[5] = c12;
    row[6] = c02; row[7] = c12; row[8] = c22;
    __syncthreads();

    // ---- coalesced stride-1 flush: 9 full-line wave stores ----
    float* op = out + base * 9;
    const long long orem = 9LL * n - base * 9;
    #pragma unroll
    for (int k = 0; k < 9; ++k) {
        int idx = tid + k * NTH;
        if (idx < orem) op[idx] = smem[idx];
    }
}

extern "C" void kernel_launch(void* const* d_in, const int* in_sizes, int n_in,
                              void* d_out, int out_size, void* d_ws, size_t ws_size,
                              hipStream_t stream) {
    const float* rot   = (const float*)d_in[0];   // (N,4) f32
    const float* scale = (const float*)d_in[1];   // (N,3) f32
    float* out = (float*)d_out;                   // (N,3,3) f32

    const long long n = (long long)in_sizes[0] / 4;
    const long long blocks = (n + NTH - 1) / NTH;
    gauss_cov_kernel<<<(dim3)(unsigned)blocks, NTH, 0, stream>>>(rot, scale, out, n);
}

// Round 4
// 408.546 us; speedup vs baseline: 1.0224x; 1.0224x over previous
//
#include <hip/hip_runtime.h>

typedef float f32x4 __attribute__((ext_vector_type(4)));

#define NTH 256

__global__ __launch_bounds__(NTH) void gauss_cov_kernel(
    const float* __restrict__ rot,
    const float* __restrict__ scale,
    float* __restrict__ out,
    long long n)
{
    __shared__ float s_scale[NTH * 3];   // 3 KB
    __shared__ float s_out[NTH * 9];     // 9 KB

    const int tid = threadIdx.x;
    const long long base = (long long)blockIdx.x * NTH;
    const long long i = base + tid;
    const bool full = (base + NTH) <= n;   // true for every block when N % NTH == 0

    // ---- stage scale into LDS: 768 floats = 192 x float4, coalesced ----
    if (full) {
        if (tid < 192) {
            const f32x4* sp4 = (const f32x4*)(scale + base * 3);  // 16B-aligned: base*12B mult of 3072
            ((f32x4*)s_scale)[tid] = __builtin_nontemporal_load(sp4 + tid);
        }
    } else {
        const float* sp = scale + base * 3;
        const long long srem = 3 * n - base * 3;
        for (int k = tid; k < NTH * 3; k += NTH)
            s_scale[k] = (k < srem) ? sp[k] : 0.0f;
    }
    __syncthreads();

    // stride-3 LDS read: gcd(3,32)=1 -> 2 lanes/bank over wave64 = conflict-free
    const float s0 = s_scale[tid * 3 + 0];
    const float s1 = s_scale[tid * 3 + 1];
    const float s2 = s_scale[tid * 3 + 2];

    // ---- quaternion: one aligned float4 per thread, coalesced ----
    float c00 = 0.f, c01 = 0.f, c02 = 0.f, c11 = 0.f, c12 = 0.f, c22 = 0.f;
    if (i < n) {
        const f32x4 q = __builtin_nontemporal_load((const f32x4*)rot + i);
        float w = q.x, x = q.y, y = q.z, z = q.w;
        const float inv = rsqrtf(w * w + x * x + y * y + z * z);
        w *= inv; x *= inv; y *= inv; z *= inv;

        const float r00 = 1.f - 2.f * (y * y + z * z);
        const float r01 = 2.f * (x * y - w * z);
        const float r02 = 2.f * (x * z + w * y);
        const float r10 = 2.f * (x * y + w * z);
        const float r11 = 1.f - 2.f * (x * x + z * z);
        const float r12 = 2.f * (y * z - w * x);
        const float r20 = 2.f * (x * z - w * y);
        const float r21 = 2.f * (y * z + w * x);
        const float r22 = 1.f - 2.f * (x * x + y * y);

        const float m00 = r00 * s0, m01 = r01 * s1, m02 = r02 * s2;
        const float m10 = r10 * s0, m11 = r11 * s1, m12 = r12 * s2;
        const float m20 = r20 * s0, m21 = r21 * s1, m22 = r22 * s2;

        c00 = m00 * m00 + m01 * m01 + m02 * m02;
        c01 = m00 * m10 + m01 * m11 + m02 * m12;
        c02 = m00 * m20 + m01 * m21 + m02 * m22;
        c11 = m10 * m10 + m11 * m11 + m12 * m12;
        c12 = m10 * m20 + m11 * m21 + m12 * m22;
        c22 = m20 * m20 + m21 * m21 + m22 * m22;
    }

    // ---- stage symmetric 3x3 into LDS (stride-9 writes: odd stride = conflict-free) ----
    __syncthreads();
    float* row = s_out + tid * 9;
    row[0] = c00; row[1] = c01; row[2] = c02;
    row[3] = c01; row[4] = c11; row[5] = c12;
    row[6] = c02; row[7] = c12; row[8] = c22;
    __syncthreads();

    // ---- flush 2304 floats = 576 x float4: ds_read_b128 + global_store_dwordx4 nt ----
    if (full) {
        f32x4* op4 = (f32x4*)(out + base * 9);      // 16B-aligned: base*36B mult of 9216
        const f32x4* so4 = (const f32x4*)s_out;
        __builtin_nontemporal_store(so4[tid],       op4 + tid);
        __builtin_nontemporal_store(so4[tid + 256], op4 + tid + 256);
        if (tid < 64)
            __builtin_nontemporal_store(so4[tid + 512], op4 + tid + 512);
    } else {
        float* op = out + base * 9;
        const long long orem = 9 * n - base * 9;
        for (int k = tid; k < NTH * 9; k += NTH)
            if (k < orem) op[k] = s_out[k];
    }
}

extern "C" void kernel_launch(void* const* d_in, const int* in_sizes, int n_in,
                              void* d_out, int out_size, void* d_ws, size_t ws_size,
                              hipStream_t stream) {
    const float* rot   = (const float*)d_in[0];   // (N,4) f32
    const float* scale = (const float*)d_in[1];   // (N,3) f32
    float* out = (float*)d_out;                   // (N,3,3) f32

    const long long n = (long long)in_sizes[0] / 4;
    const long long blocks = (n + NTH - 1) / NTH;
    gauss_cov_kernel<<<(dim3)(unsigned)blocks, NTH, 0, stream>>>(rot, scale, out, n);
}